// Round 13
// baseline (348.769 us; speedup 1.0000x reference)
//
#include <hip/hip_runtime.h>
#include <hip/hip_bf16.h>

// EdgeBlock: out[e] = relu(concat(edge[e], node[recv[e]], node[send[e]], g) @ W1 + b1) @ W2 + b2
// Round 13 = r11 chassis (best, 121.5us) + own-fragment register reuse:
//  - wave keeps its 6 staged A-frags in registers; GEMM1's mt==w quarter runs from regs
//    (12 MFMAs issue right after B1, no ds_read dependency; 24->18 ds_reads/tile/wave)
//  - other quarters iterate mt=(w+i)&3 so waves start on different LDS regions
//  - __launch_bounds__(256,4) pins VGPR <= 128 (4 waves/SIMD preserved)
// unchanged: frag-order pinned weights, sigma+SWZ h layout, 2 lgkm-only barriers/tile,
// T14 1-deep gather prefetch, 2-deep idx prefetch, setprio on MFMA clusters, grid 1024.

typedef __bf16 bf16x8 __attribute__((ext_vector_type(8)));
typedef __bf16 bf16x2 __attribute__((ext_vector_type(2)));
typedef float f32x4 __attribute__((ext_vector_type(4)));

#define GRID_MAIN 1024
#define SWZ(x) ((x) ^ (((x) >> 3) & 7))
// ws layout:
//   [0, 49152)       W1F bf16 frag-order
//   [49152, 65536)   W2F bf16 frag-order, sigma (h physical-k permutation) baked in
//   [65536, 66048)   g1 f32 [128] = b1 + global_attr @ W1[192:256]
//   [66560, ...)     node_bf16 [N][64]
#define WS_NODEBF_OFF 66560

__global__ void prep_kernel(const float* __restrict__ W1, const float* __restrict__ b1,
                            const float* __restrict__ W2, const float* __restrict__ gattr,
                            __bf16* __restrict__ W1F, __bf16* __restrict__ W2F,
                            float* __restrict__ g1) {
    int tid = blockIdx.x * blockDim.x + threadIdx.x;
    if (tid < 128 * 192) {
        int n = tid / 192, k = tid % 192;
        int w = n >> 5, nt2 = (n >> 4) & 1, c = n & 15;
        int f = k >> 5, g = (k >> 3) & 3, j = k & 7;
        W1F[((((w * 2 + nt2) * 6 + f) * 64) + c + 16 * g) * 8 + j] = (__bf16)W1[k * 128 + n];
    } else if (tid < 128 * 192 + 64 * 128) {
        int t = tid - 128 * 192;
        int n = t / 128, p = t % 128;   // p = PHYSICAL k slot (h_frag column)
        int w = n >> 4, c = n & 15;
        int ks = p >> 5, g = (p >> 3) & 3, j = p & 7;
        // sigma: physical p = w1*32 + 2*cc + half  <->  klog = w1*32 + half*16 + cc
        int klog = (p >> 5) * 32 + (p & 1) * 16 + ((p >> 1) & 15);
        W2F[(((w * 4 + ks) * 64) + c + 16 * g) * 8 + j] = (__bf16)W2[klog * 64 + n];
    } else if (tid < 128 * 192 + 64 * 128 + 128) {
        int n = tid - (128 * 192 + 64 * 128);
        float acc = b1[n];
        for (int j = 0; j < 64; ++j) acc += gattr[j] * W1[(192 + j) * 128 + n];
        g1[n] = acc;
    }
}

__global__ __launch_bounds__(256) void node_conv_kernel(const float* __restrict__ nf,
                                                        __bf16* __restrict__ nb, int n8) {
    int t = blockIdx.x * blockDim.x + threadIdx.x;
    if (t < n8) {
        f32x4 a = *(const f32x4*)(nf + (long)t * 8);
        f32x4 b = *(const f32x4*)(nf + (long)t * 8 + 4);
        bf16x8 o;
#pragma unroll
        for (int j = 0; j < 4; ++j) { o[j] = (__bf16)a[j]; o[4 + j] = (__bf16)b[j]; }
        *(bf16x8*)(nb + (long)t * 8) = o;
    }
}

__device__ __forceinline__ f32x4 mk4(float v) {
    f32x4 r; r[0] = v; r[1] = v; r[2] = v; r[3] = v; return r;
}

__device__ __forceinline__ bf16x8 cvt8(f32x4 lo, f32x4 hi) {
    bf16x8 t;
#pragma unroll
    for (int j = 0; j < 4; ++j) { t[j] = (__bf16)lo[j]; t[4 + j] = (__bf16)hi[j]; }
    return t;
}

__global__ __launch_bounds__(256, 4) void edge_mlp_kernel(
    const float* __restrict__ edge_feats, const __bf16* __restrict__ node_bf,
    const int* __restrict__ senders, const int* __restrict__ receivers,
    const __bf16* __restrict__ W1F, const __bf16* __restrict__ W2F,
    const float* __restrict__ g1, const float* __restrict__ b2,
    float* __restrict__ out, int E, int numTiles)
{
    // A tile [mt=4][f=6][lane=64]x16B at bytes [0,24576); h tile at bytes [24576,40960)
    __shared__ __bf16 smem[20480];   // 40960 B

    const int lane = threadIdx.x & 63;
    const int w    = threadIdx.x >> 6;
    const int c    = lane & 15;
    const int g    = lane >> 4;
    const int G    = gridDim.x;

    // ---- pinned weights: 16 coalesced dwordx4 loads, once per block ----
    bf16x8 wb1[2][6];
#pragma unroll
    for (int nt2 = 0; nt2 < 2; ++nt2)
#pragma unroll
        for (int f = 0; f < 6; ++f)
            wb1[nt2][f] = *(const bf16x8*)(W1F + (((w * 2 + nt2) * 6 + f) * 64 + lane) * 8);
    bf16x8 wb2[4];
#pragma unroll
    for (int ks = 0; ks < 4; ++ks)
        wb2[ks] = *(const bf16x8*)(W2F + ((w * 4 + ks) * 64 + lane) * 8);
    const float g1v0 = g1[w * 32 + c];
    const float g1v1 = g1[w * 32 + 16 + c];
    const float b2v  = b2[w * 16 + c];

    // hoisted swizzled READ slot for GEMM2
    const int sr = SWZ(c * 4 + g);

    // ---- prologue ----
    bf16x8 snr0, snr1, sns0, sns1;
    f32x4 se0, se1, se2, se3;
    int iRa, iSa, iRb, iSb;
    {
        long r0 = (long)blockIdx.x * 64 + w * 16 + c;
        if (r0 > (long)E - 1) r0 = (long)E - 1;
        int iR0 = receivers[r0], iS0 = senders[r0];
        const __bf16* pr = node_bf + ((long)iR0 << 6) + g * 8;
        const __bf16* ps = node_bf + ((long)iS0 << 6) + g * 8;
        snr0 = *(const bf16x8*)(pr);
        snr1 = *(const bf16x8*)(pr + 32);
        sns0 = *(const bf16x8*)(ps);
        sns1 = *(const bf16x8*)(ps + 32);
        const float* pe = edge_feats + (r0 << 6) + g * 8;
        se0 = *(const f32x4*)(pe);      se1 = *(const f32x4*)(pe + 4);
        se2 = *(const f32x4*)(pe + 32); se3 = *(const f32x4*)(pe + 36);
        long r1 = ((long)blockIdx.x + G) * 64 + w * 16 + c;
        if (r1 > (long)E - 1) r1 = (long)E - 1;
        iRa = receivers[r1]; iSa = senders[r1];
        long r2 = ((long)blockIdx.x + 2L * G) * 64 + w * 16 + c;
        if (r2 > (long)E - 1) r2 = (long)E - 1;
        iRb = receivers[r2]; iSb = senders[r2];
    }

    for (int t = blockIdx.x; t < numTiles; t += G) {
        // ---- stage current tile -> A; keep own frags in registers ----
        bf16x8 aown0 = cvt8(se0, se1);
        bf16x8 aown1 = cvt8(se2, se3);
        bf16x8 aown2 = snr0, aown3 = snr1, aown4 = sns0, aown5 = sns1;
        __bf16* ab = smem + w * 3072 + lane * 8;
        *(bf16x8*)(ab)        = aown0;
        *(bf16x8*)(ab + 512)  = aown1;
        *(bf16x8*)(ab + 1024) = aown2;
        *(bf16x8*)(ab + 1536) = aown3;
        *(bf16x8*)(ab + 2048) = aown4;
        *(bf16x8*)(ab + 2560) = aown5;

        // ---- T14: issue NEXT tile's gathers; rotate 2-deep idx ----
        {
            const __bf16* pr = node_bf + ((long)iRa << 6) + g * 8;
            const __bf16* ps = node_bf + ((long)iSa << 6) + g * 8;
            snr0 = *(const bf16x8*)(pr);
            snr1 = *(const bf16x8*)(pr + 32);
            sns0 = *(const bf16x8*)(ps);
            sns1 = *(const bf16x8*)(ps + 32);
            long rce = ((long)t + G) * 64 + w * 16 + c;
            if (rce > (long)E - 1) rce = (long)E - 1;
            const float* pe = edge_feats + (rce << 6) + g * 8;
            se0 = *(const f32x4*)(pe);      se1 = *(const f32x4*)(pe + 4);
            se2 = *(const f32x4*)(pe + 32); se3 = *(const f32x4*)(pe + 36);
            iRa = iRb; iSa = iSb;
            long r3 = ((long)t + 3L * G) * 64 + w * 16 + c;
            if (r3 > (long)E - 1) r3 = (long)E - 1;
            iRb = receivers[r3]; iSb = senders[r3];
        }
        __builtin_amdgcn_sched_barrier(0);

        // B1: A visible; VMEM prefetch stays in flight (lgkm-only)
        asm volatile("s_waitcnt lgkmcnt(0)" ::: "memory");
        __builtin_amdgcn_s_barrier();

        // ---- GEMM1: acc[i] covers edge rows mt=(w+i)&3; i=0 from registers ----
        f32x4 acc0[4], acc1[4];
#pragma unroll
        for (int i = 0; i < 4; ++i) { acc0[i] = mk4(g1v0); acc1[i] = mk4(g1v1); }
        __builtin_amdgcn_s_setprio(1);
        // i = 0 (mt == w): pure-register MFMAs, no ds_read dependency
        acc0[0] = __builtin_amdgcn_mfma_f32_16x16x32_bf16(aown0, wb1[0][0], acc0[0], 0, 0, 0);
        acc1[0] = __builtin_amdgcn_mfma_f32_16x16x32_bf16(aown0, wb1[1][0], acc1[0], 0, 0, 0);
        acc0[0] = __builtin_amdgcn_mfma_f32_16x16x32_bf16(aown1, wb1[0][1], acc0[0], 0, 0, 0);
        acc1[0] = __builtin_amdgcn_mfma_f32_16x16x32_bf16(aown1, wb1[1][1], acc1[0], 0, 0, 0);
        acc0[0] = __builtin_amdgcn_mfma_f32_16x16x32_bf16(aown2, wb1[0][2], acc0[0], 0, 0, 0);
        acc1[0] = __builtin_amdgcn_mfma_f32_16x16x32_bf16(aown2, wb1[1][2], acc1[0], 0, 0, 0);
        acc0[0] = __builtin_amdgcn_mfma_f32_16x16x32_bf16(aown3, wb1[0][3], acc0[0], 0, 0, 0);
        acc1[0] = __builtin_amdgcn_mfma_f32_16x16x32_bf16(aown3, wb1[1][3], acc1[0], 0, 0, 0);
        acc0[0] = __builtin_amdgcn_mfma_f32_16x16x32_bf16(aown4, wb1[0][4], acc0[0], 0, 0, 0);
        acc1[0] = __builtin_amdgcn_mfma_f32_16x16x32_bf16(aown4, wb1[1][4], acc1[0], 0, 0, 0);
        acc0[0] = __builtin_amdgcn_mfma_f32_16x16x32_bf16(aown5, wb1[0][5], acc0[0], 0, 0, 0);
        acc1[0] = __builtin_amdgcn_mfma_f32_16x16x32_bf16(aown5, wb1[1][5], acc1[0], 0, 0, 0);
        // i = 1..3: other quarters from LDS (each wave starts on a different region)
#pragma unroll
        for (int i = 1; i < 4; ++i) {
            const int mt = (w + i) & 3;   // runtime uniform, address-only
#pragma unroll
            for (int f = 0; f < 6; ++f) {
                bf16x8 a = *(const bf16x8*)(smem + ((mt * 6 + f) * 64 + lane) * 8);
                acc0[i] = __builtin_amdgcn_mfma_f32_16x16x32_bf16(a, wb1[0][f], acc0[i], 0, 0, 0);
                acc1[i] = __builtin_amdgcn_mfma_f32_16x16x32_bf16(a, wb1[1][f], acc1[i], 0, 0, 0);
            }
        }
        __builtin_amdgcn_s_setprio(0);

        // ---- relu -> swizzled frag-order h (row tile mt=(w+i)&3) ----
#pragma unroll
        for (int i = 0; i < 4; ++i) {
            const int mt = (w + i) & 3;
#pragma unroll
            for (int r = 0; r < 4; ++r) {
                float v0 = acc0[i][r]; v0 = v0 > 0.f ? v0 : 0.f;
                float v1 = acc1[i][r]; v1 = v1 > 0.f ? v1 : 0.f;
                bf16x2 pk; pk[0] = (__bf16)v0; pk[1] = (__bf16)v1;
                int s = SWZ(g * 16 + r * 4 + (c >> 2));
                *(bf16x2*)&smem[12288 + (mt * 4 + w) * 512 + s * 8 + ((c & 3) << 1)] = pk;
            }
        }

        // B2: h visible (also orders A-WAR for next iteration's stage)
        asm volatile("s_waitcnt lgkmcnt(0)" ::: "memory");
        __builtin_amdgcn_s_barrier();

        // ---- GEMM2 (setprio-wrapped) ----
        f32x4 acc2[4];
#pragma unroll
        for (int mt = 0; mt < 4; ++mt) acc2[mt] = mk4(b2v);
        __builtin_amdgcn_s_setprio(1);
#pragma unroll
        for (int mt = 0; mt < 4; ++mt)
#pragma unroll
            for (int ks = 0; ks < 4; ++ks) {
                bf16x8 ah = *(const bf16x8*)&smem[12288 + (mt * 4 + ks) * 512 + sr * 8];
                acc2[mt] = __builtin_amdgcn_mfma_f32_16x16x32_bf16(ah, wb2[ks], acc2[mt], 0, 0, 0);
            }
        __builtin_amdgcn_s_setprio(0);

        // ---- stores ----
#pragma unroll
        for (int mt = 0; mt < 4; ++mt)
#pragma unroll
            for (int r = 0; r < 4; ++r) {
                long orow = (long)t * 64 + mt * 16 + g * 4 + r;
                if (orow < E) out[orow * 64 + w * 16 + c] = acc2[mt][r];
            }
        // no end barrier: next B1 orders h-WAR, B2 already ordered A-WAR
    }
}

// fallback (ws too small for node table)
__global__ __launch_bounds__(256) void edge_mlp_fallback(
    const float* __restrict__ edge_feats, const float* __restrict__ node_feats,
    const int* __restrict__ senders, const int* __restrict__ receivers,
    const __bf16* __restrict__ W1F, const __bf16* __restrict__ W2F,
    const float* __restrict__ g1, const float* __restrict__ b2,
    float* __restrict__ out, int E, int numTiles)
{
    __shared__ __bf16 A_lds[4 * 6 * 64 * 8];
    __shared__ __bf16 h_frag[4 * 4 * 64 * 8];
    const int lane = threadIdx.x & 63;
    const int w = threadIdx.x >> 6;
    const int c = lane & 15;
    const int g = lane >> 4;
    const int G = gridDim.x;

    bf16x8 wb1[2][6];
#pragma unroll
    for (int nt2 = 0; nt2 < 2; ++nt2)
#pragma unroll
        for (int f = 0; f < 6; ++f)
            wb1[nt2][f] = *(const bf16x8*)(W1F + (((w * 2 + nt2) * 6 + f) * 64 + lane) * 8);
    bf16x8 wb2[4];
#pragma unroll
    for (int ks = 0; ks < 4; ++ks)
        wb2[ks] = *(const bf16x8*)(W2F + ((w * 4 + ks) * 64 + lane) * 8);
    const float g1v0 = g1[w * 32 + c];
    const float g1v1 = g1[w * 32 + 16 + c];
    const float b2v  = b2[w * 16 + c];
    const int sr = SWZ(c * 4 + g);

    for (int t = blockIdx.x; t < numTiles; t += G) {
        long rowc = (long)t * 64 + w * 16 + c;
        if (rowc > (long)E - 1) rowc = (long)E - 1;
        int iR = receivers[rowc], iS = senders[rowc];
        const float* pr = node_feats + ((long)iR << 6) + g * 8;
        const float* ps = node_feats + ((long)iS << 6) + g * 8;
        const float* pe = edge_feats + (rowc << 6) + g * 8;
        f32x4 e0a = *(const f32x4*)(pe),      e0b = *(const f32x4*)(pe + 4);
        f32x4 e1a = *(const f32x4*)(pe + 32), e1b = *(const f32x4*)(pe + 36);
        f32x4 r0a = *(const f32x4*)(pr),      r0b = *(const f32x4*)(pr + 4);
        f32x4 r1a = *(const f32x4*)(pr + 32), r1b = *(const f32x4*)(pr + 36);
        f32x4 s0a = *(const f32x4*)(ps),      s0b = *(const f32x4*)(ps + 4);
        f32x4 s1a = *(const f32x4*)(ps + 32), s1b = *(const f32x4*)(ps + 36);

        __bf16* ab = A_lds + w * 6 * 512 + lane * 8;
        *(bf16x8*)(ab)        = cvt8(e0a, e0b);
        *(bf16x8*)(ab + 512)  = cvt8(e1a, e1b);
        *(bf16x8*)(ab + 1024) = cvt8(r0a, r0b);
        *(bf16x8*)(ab + 1536) = cvt8(r1a, r1b);
        *(bf16x8*)(ab + 2048) = cvt8(s0a, s0b);
        *(bf16x8*)(ab + 2560) = cvt8(s1a, s1b);
        __syncthreads();

        f32x4 acc0[4], acc1[4];
#pragma unroll
        for (int mt = 0; mt < 4; ++mt) { acc0[mt] = mk4(g1v0); acc1[mt] = mk4(g1v1); }
#pragma unroll
        for (int mt = 0; mt < 4; ++mt)
#pragma unroll
            for (int f = 0; f < 6; ++f) {
                bf16x8 a = *(const bf16x8*)(A_lds + ((mt * 6 + f) * 64 + lane) * 8);
                acc0[mt] = __builtin_amdgcn_mfma_f32_16x16x32_bf16(a, wb1[0][f], acc0[mt], 0, 0, 0);
                acc1[mt] = __builtin_amdgcn_mfma_f32_16x16x32_bf16(a, wb1[1][f], acc1[mt], 0, 0, 0);
            }
#pragma unroll
        for (int mt = 0; mt < 4; ++mt)
#pragma unroll
            for (int r = 0; r < 4; ++r) {
                float v0 = acc0[mt][r]; v0 = v0 > 0.f ? v0 : 0.f;
                float v1 = acc1[mt][r]; v1 = v1 > 0.f ? v1 : 0.f;
                bf16x2 pk; pk[0] = (__bf16)v0; pk[1] = (__bf16)v1;
                int s = SWZ(g * 16 + r * 4 + (c >> 2));
                *(bf16x2*)&h_frag[((mt * 4 + w) * 512) + s * 8 + ((c & 3) << 1)] = pk;
            }
        __syncthreads();

        f32x4 acc2[4];
#pragma unroll
        for (int mt = 0; mt < 4; ++mt) acc2[mt] = mk4(b2v);
#pragma unroll
        for (int mt = 0; mt < 4; ++mt)
#pragma unroll
            for (int ks = 0; ks < 4; ++ks) {
                bf16x8 ah = *(const bf16x8*)&h_frag[(mt * 4 + ks) * 512 + sr * 8];
                acc2[mt] = __builtin_amdgcn_mfma_f32_16x16x32_bf16(ah, wb2[ks], acc2[mt], 0, 0, 0);
            }
#pragma unroll
        for (int mt = 0; mt < 4; ++mt)
#pragma unroll
            for (int r = 0; r < 4; ++r) {
                long orow = (long)t * 64 + mt * 16 + g * 4 + r;
                if (orow < E) out[orow * 64 + w * 16 + c] = acc2[mt][r];
            }
        __syncthreads();
    }
}

extern "C" void kernel_launch(void* const* d_in, const int* in_sizes, int n_in,
                              void* d_out, int out_size, void* d_ws, size_t ws_size,
                              hipStream_t stream) {
    const float* edge_feats = (const float*)d_in[0];
    const float* node_feats = (const float*)d_in[1];
    const float* gattr      = (const float*)d_in[2];
    const int*   senders    = (const int*)d_in[3];
    const int*   receivers  = (const int*)d_in[4];
    const float* W1         = (const float*)d_in[5];
    const float* b1         = (const float*)d_in[6];
    const float* W2         = (const float*)d_in[7];
    const float* b2         = (const float*)d_in[8];
    float* out = (float*)d_out;

    const int E = in_sizes[3];        // N_EDGES
    const int N = in_sizes[1] / 64;   // N_NODES

    char* ws = (char*)d_ws;
    __bf16* W1F = (__bf16*)ws;
    __bf16* W2F = (__bf16*)(ws + 49152);
    float*  g1  = (float*)(ws + 49152 + 16384);
    __bf16* nodeBF = (__bf16*)(ws + WS_NODEBF_OFF);

    const size_t ws_needed = (size_t)WS_NODEBF_OFF + (size_t)N * 64 * 2;
    const bool useNB = ws_size >= ws_needed;

    int prep_total = 128 * 192 + 64 * 128 + 128;
    prep_kernel<<<(prep_total + 255) / 256, 256, 0, stream>>>(W1, b1, W2, gattr, W1F, W2F, g1);

    const int numTiles = (E + 63) / 64;
    int grid = numTiles < GRID_MAIN ? numTiles : GRID_MAIN;
    if (useNB) {
        int n8 = N * 8;
        node_conv_kernel<<<(n8 + 255) / 256, 256, 0, stream>>>(node_feats, nodeBF, n8);
        edge_mlp_kernel<<<grid, 256, 0, stream>>>(edge_feats, nodeBF, senders, receivers,
                                                  W1F, W2F, g1, b2, out, E, numTiles);
    } else {
        edge_mlp_fallback<<<grid, 256, 0, stream>>>(edge_feats, node_feats, senders, receivers,
                                                    W1F, W2F, g1, b2, out, E, numTiles);
    }
}

// Round 14
// 121.056 us; speedup vs baseline: 2.8811x; 2.8811x over previous
//
#include <hip/hip_runtime.h>
#include <hip/hip_bf16.h>

// EdgeBlock: out[e] = relu(concat(edge[e], node[recv[e]], node[send[e]], g) @ W1 + b1) @ W2 + b2
// Round 14 = EXACT REVERT to round-11 optimum (121.5 us), restoring from r13's spill.
// Structure: 64-edge tiles, 4 waves; frag-order pinned weights (prep-transposed ws tables);
// bf16 node table; global-attr prefolded into acc init (K=192); sigma+SWZ h layout;
// 2 lgkm-only raw barriers/tile; T14 1-deep gather prefetch + 2-deep idx prefetch;
// setprio(1) on MFMA clusters; grid 1024 (4 blocks/CU, one generation).
// NOTE: no __launch_bounds__ min-waves arg -- r13 showed it forces a 64-VGPR clamp + spill.

typedef __bf16 bf16x8 __attribute__((ext_vector_type(8)));
typedef __bf16 bf16x2 __attribute__((ext_vector_type(2)));
typedef float f32x4 __attribute__((ext_vector_type(4)));

#define GRID_MAIN 1024
#define SWZ(x) ((x) ^ (((x) >> 3) & 7))
// ws layout:
//   [0, 49152)       W1F bf16 frag-order
//   [49152, 65536)   W2F bf16 frag-order, sigma (h physical-k permutation) baked in
//   [65536, 66048)   g1 f32 [128] = b1 + global_attr @ W1[192:256]
//   [66560, ...)     node_bf16 [N][64]
#define WS_NODEBF_OFF 66560

__global__ void prep_kernel(const float* __restrict__ W1, const float* __restrict__ b1,
                            const float* __restrict__ W2, const float* __restrict__ gattr,
                            __bf16* __restrict__ W1F, __bf16* __restrict__ W2F,
                            float* __restrict__ g1) {
    int tid = blockIdx.x * blockDim.x + threadIdx.x;
    if (tid < 128 * 192) {
        int n = tid / 192, k = tid % 192;
        int w = n >> 5, nt2 = (n >> 4) & 1, c = n & 15;
        int f = k >> 5, g = (k >> 3) & 3, j = k & 7;
        W1F[((((w * 2 + nt2) * 6 + f) * 64) + c + 16 * g) * 8 + j] = (__bf16)W1[k * 128 + n];
    } else if (tid < 128 * 192 + 64 * 128) {
        int t = tid - 128 * 192;
        int n = t / 128, p = t % 128;   // p = PHYSICAL k slot (h_frag column)
        int w = n >> 4, c = n & 15;
        int ks = p >> 5, g = (p >> 3) & 3, j = p & 7;
        // sigma: physical p = w1*32 + 2*cc + half  <->  klog = w1*32 + half*16 + cc
        int klog = (p >> 5) * 32 + (p & 1) * 16 + ((p >> 1) & 15);
        W2F[(((w * 4 + ks) * 64) + c + 16 * g) * 8 + j] = (__bf16)W2[klog * 64 + n];
    } else if (tid < 128 * 192 + 64 * 128 + 128) {
        int n = tid - (128 * 192 + 64 * 128);
        float acc = b1[n];
        for (int j = 0; j < 64; ++j) acc += gattr[j] * W1[(192 + j) * 128 + n];
        g1[n] = acc;
    }
}

__global__ __launch_bounds__(256) void node_conv_kernel(const float* __restrict__ nf,
                                                        __bf16* __restrict__ nb, int n8) {
    int t = blockIdx.x * blockDim.x + threadIdx.x;
    if (t < n8) {
        f32x4 a = *(const f32x4*)(nf + (long)t * 8);
        f32x4 b = *(const f32x4*)(nf + (long)t * 8 + 4);
        bf16x8 o;
#pragma unroll
        for (int j = 0; j < 4; ++j) { o[j] = (__bf16)a[j]; o[4 + j] = (__bf16)b[j]; }
        *(bf16x8*)(nb + (long)t * 8) = o;
    }
}

__device__ __forceinline__ f32x4 mk4(float v) {
    f32x4 r; r[0] = v; r[1] = v; r[2] = v; r[3] = v; return r;
}

__device__ __forceinline__ bf16x8 cvt8(f32x4 lo, f32x4 hi) {
    bf16x8 t;
#pragma unroll
    for (int j = 0; j < 4; ++j) { t[j] = (__bf16)lo[j]; t[4 + j] = (__bf16)hi[j]; }
    return t;
}

__global__ __launch_bounds__(256) void edge_mlp_kernel(
    const float* __restrict__ edge_feats, const __bf16* __restrict__ node_bf,
    const int* __restrict__ senders, const int* __restrict__ receivers,
    const __bf16* __restrict__ W1F, const __bf16* __restrict__ W2F,
    const float* __restrict__ g1, const float* __restrict__ b2,
    float* __restrict__ out, int E, int numTiles)
{
    // A tile [mt=4][f=6][lane=64]x16B at [0,12288); h tile (swizzled) at [12288,20480)
    __shared__ __bf16 smem[20480];   // 40960 B

    const int lane = threadIdx.x & 63;
    const int w    = threadIdx.x >> 6;
    const int c    = lane & 15;
    const int g    = lane >> 4;
    const int G    = gridDim.x;

    // ---- pinned weights: 16 coalesced dwordx4 loads, once per block ----
    bf16x8 wb1[2][6];
#pragma unroll
    for (int nt2 = 0; nt2 < 2; ++nt2)
#pragma unroll
        for (int f = 0; f < 6; ++f)
            wb1[nt2][f] = *(const bf16x8*)(W1F + (((w * 2 + nt2) * 6 + f) * 64 + lane) * 8);
    bf16x8 wb2[4];
#pragma unroll
    for (int ks = 0; ks < 4; ++ks)
        wb2[ks] = *(const bf16x8*)(W2F + ((w * 4 + ks) * 64 + lane) * 8);
    const float g1v0 = g1[w * 32 + c];
    const float g1v1 = g1[w * 32 + 16 + c];
    const float b2v  = b2[w * 16 + c];

    // hoisted swizzled READ slot for GEMM2
    const int sr = SWZ(c * 4 + g);

    // ---- prologue ----
    bf16x8 snr0, snr1, sns0, sns1;
    f32x4 se0, se1, se2, se3;
    int iRa, iSa, iRb, iSb;
    {
        long r0 = (long)blockIdx.x * 64 + w * 16 + c;
        if (r0 > (long)E - 1) r0 = (long)E - 1;
        int iR0 = receivers[r0], iS0 = senders[r0];
        const __bf16* pr = node_bf + ((long)iR0 << 6) + g * 8;
        const __bf16* ps = node_bf + ((long)iS0 << 6) + g * 8;
        snr0 = *(const bf16x8*)(pr);
        snr1 = *(const bf16x8*)(pr + 32);
        sns0 = *(const bf16x8*)(ps);
        sns1 = *(const bf16x8*)(ps + 32);
        const float* pe = edge_feats + (r0 << 6) + g * 8;
        se0 = *(const f32x4*)(pe);      se1 = *(const f32x4*)(pe + 4);
        se2 = *(const f32x4*)(pe + 32); se3 = *(const f32x4*)(pe + 36);
        long r1 = ((long)blockIdx.x + G) * 64 + w * 16 + c;
        if (r1 > (long)E - 1) r1 = (long)E - 1;
        iRa = receivers[r1]; iSa = senders[r1];
        long r2 = ((long)blockIdx.x + 2L * G) * 64 + w * 16 + c;
        if (r2 > (long)E - 1) r2 = (long)E - 1;
        iRb = receivers[r2]; iSb = senders[r2];
    }

    for (int t = blockIdx.x; t < numTiles; t += G) {
        // ---- stage current tile -> A ----
        __bf16* ab = smem + w * 3072 + lane * 8;
        *(bf16x8*)(ab)        = cvt8(se0, se1);
        *(bf16x8*)(ab + 512)  = cvt8(se2, se3);
        *(bf16x8*)(ab + 1024) = snr0;
        *(bf16x8*)(ab + 1536) = snr1;
        *(bf16x8*)(ab + 2048) = sns0;
        *(bf16x8*)(ab + 2560) = sns1;

        // ---- T14: issue NEXT tile's gathers; rotate 2-deep idx ----
        {
            const __bf16* pr = node_bf + ((long)iRa << 6) + g * 8;
            const __bf16* ps = node_bf + ((long)iSa << 6) + g * 8;
            snr0 = *(const bf16x8*)(pr);
            snr1 = *(const bf16x8*)(pr + 32);
            sns0 = *(const bf16x8*)(ps);
            sns1 = *(const bf16x8*)(ps + 32);
            long rce = ((long)t + G) * 64 + w * 16 + c;
            if (rce > (long)E - 1) rce = (long)E - 1;
            const float* pe = edge_feats + (rce << 6) + g * 8;
            se0 = *(const f32x4*)(pe);      se1 = *(const f32x4*)(pe + 4);
            se2 = *(const f32x4*)(pe + 32); se3 = *(const f32x4*)(pe + 36);
            iRa = iRb; iSa = iSb;
            long r3 = ((long)t + 3L * G) * 64 + w * 16 + c;
            if (r3 > (long)E - 1) r3 = (long)E - 1;
            iRb = receivers[r3]; iSb = senders[r3];
        }
        __builtin_amdgcn_sched_barrier(0);

        // B1: A visible; VMEM prefetch stays in flight (lgkm-only)
        asm volatile("s_waitcnt lgkmcnt(0)" ::: "memory");
        __builtin_amdgcn_s_barrier();

        // ---- GEMM1 (setprio-wrapped) ----
        f32x4 acc0[4], acc1[4];
#pragma unroll
        for (int mt = 0; mt < 4; ++mt) { acc0[mt] = mk4(g1v0); acc1[mt] = mk4(g1v1); }
        __builtin_amdgcn_s_setprio(1);
#pragma unroll
        for (int mt = 0; mt < 4; ++mt)
#pragma unroll
            for (int f = 0; f < 6; ++f) {
                bf16x8 a = *(const bf16x8*)(smem + ((mt * 6 + f) * 64 + lane) * 8);
                acc0[mt] = __builtin_amdgcn_mfma_f32_16x16x32_bf16(a, wb1[0][f], acc0[mt], 0, 0, 0);
                acc1[mt] = __builtin_amdgcn_mfma_f32_16x16x32_bf16(a, wb1[1][f], acc1[mt], 0, 0, 0);
            }
        __builtin_amdgcn_s_setprio(0);

        // ---- relu -> swizzled frag-order h ----
#pragma unroll
        for (int mt = 0; mt < 4; ++mt)
#pragma unroll
            for (int r = 0; r < 4; ++r) {
                float v0 = acc0[mt][r]; v0 = v0 > 0.f ? v0 : 0.f;
                float v1 = acc1[mt][r]; v1 = v1 > 0.f ? v1 : 0.f;
                bf16x2 pk; pk[0] = (__bf16)v0; pk[1] = (__bf16)v1;
                int s = SWZ(g * 16 + r * 4 + (c >> 2));
                *(bf16x2*)&smem[12288 + (mt * 4 + w) * 512 + s * 8 + ((c & 3) << 1)] = pk;
            }

        // B2: h visible (also orders A-WAR for next iteration's stage)
        asm volatile("s_waitcnt lgkmcnt(0)" ::: "memory");
        __builtin_amdgcn_s_barrier();

        // ---- GEMM2 (setprio-wrapped) ----
        f32x4 acc2[4];
#pragma unroll
        for (int mt = 0; mt < 4; ++mt) acc2[mt] = mk4(b2v);
        __builtin_amdgcn_s_setprio(1);
#pragma unroll
        for (int mt = 0; mt < 4; ++mt)
#pragma unroll
            for (int ks = 0; ks < 4; ++ks) {
                bf16x8 ah = *(const bf16x8*)&smem[12288 + (mt * 4 + ks) * 512 + sr * 8];
                acc2[mt] = __builtin_amdgcn_mfma_f32_16x16x32_bf16(ah, wb2[ks], acc2[mt], 0, 0, 0);
            }
        __builtin_amdgcn_s_setprio(0);

        // ---- stores ----
#pragma unroll
        for (int mt = 0; mt < 4; ++mt)
#pragma unroll
            for (int r = 0; r < 4; ++r) {
                long orow = (long)t * 64 + mt * 16 + g * 4 + r;
                if (orow < E) out[orow * 64 + w * 16 + c] = acc2[mt][r];
            }
        // no end barrier: next B1 orders h-WAR, B2 already ordered A-WAR
    }
}

// fallback (ws too small for node table)
__global__ __launch_bounds__(256) void edge_mlp_fallback(
    const float* __restrict__ edge_feats, const float* __restrict__ node_feats,
    const int* __restrict__ senders, const int* __restrict__ receivers,
    const __bf16* __restrict__ W1F, const __bf16* __restrict__ W2F,
    const float* __restrict__ g1, const float* __restrict__ b2,
    float* __restrict__ out, int E, int numTiles)
{
    __shared__ __bf16 A_lds[4 * 6 * 64 * 8];
    __shared__ __bf16 h_frag[4 * 4 * 64 * 8];
    const int lane = threadIdx.x & 63;
    const int w = threadIdx.x >> 6;
    const int c = lane & 15;
    const int g = lane >> 4;
    const int G = gridDim.x;

    bf16x8 wb1[2][6];
#pragma unroll
    for (int nt2 = 0; nt2 < 2; ++nt2)
#pragma unroll
        for (int f = 0; f < 6; ++f)
            wb1[nt2][f] = *(const bf16x8*)(W1F + (((w * 2 + nt2) * 6 + f) * 64 + lane) * 8);
    bf16x8 wb2[4];
#pragma unroll
    for (int ks = 0; ks < 4; ++ks)
        wb2[ks] = *(const bf16x8*)(W2F + ((w * 4 + ks) * 64 + lane) * 8);
    const float g1v0 = g1[w * 32 + c];
    const float g1v1 = g1[w * 32 + 16 + c];
    const float b2v  = b2[w * 16 + c];
    const int sr = SWZ(c * 4 + g);

    for (int t = blockIdx.x; t < numTiles; t += G) {
        long rowc = (long)t * 64 + w * 16 + c;
        if (rowc > (long)E - 1) rowc = (long)E - 1;
        int iR = receivers[rowc], iS = senders[rowc];
        const float* pr = node_feats + ((long)iR << 6) + g * 8;
        const float* ps = node_feats + ((long)iS << 6) + g * 8;
        const float* pe = edge_feats + (rowc << 6) + g * 8;
        f32x4 e0a = *(const f32x4*)(pe),      e0b = *(const f32x4*)(pe + 4);
        f32x4 e1a = *(const f32x4*)(pe + 32), e1b = *(const f32x4*)(pe + 36);
        f32x4 r0a = *(const f32x4*)(pr),      r0b = *(const f32x4*)(pr + 4);
        f32x4 r1a = *(const f32x4*)(pr + 32), r1b = *(const f32x4*)(pr + 36);
        f32x4 s0a = *(const f32x4*)(ps),      s0b = *(const f32x4*)(ps + 4);
        f32x4 s1a = *(const f32x4*)(ps + 32), s1b = *(const f32x4*)(ps + 36);

        __bf16* ab = A_lds + w * 6 * 512 + lane * 8;
        *(bf16x8*)(ab)        = cvt8(e0a, e0b);
        *(bf16x8*)(ab + 512)  = cvt8(e1a, e1b);
        *(bf16x8*)(ab + 1024) = cvt8(r0a, r0b);
        *(bf16x8*)(ab + 1536) = cvt8(r1a, r1b);
        *(bf16x8*)(ab + 2048) = cvt8(s0a, s0b);
        *(bf16x8*)(ab + 2560) = cvt8(s1a, s1b);
        __syncthreads();

        f32x4 acc0[4], acc1[4];
#pragma unroll
        for (int mt = 0; mt < 4; ++mt) { acc0[mt] = mk4(g1v0); acc1[mt] = mk4(g1v1); }
#pragma unroll
        for (int mt = 0; mt < 4; ++mt)
#pragma unroll
            for (int f = 0; f < 6; ++f) {
                bf16x8 a = *(const bf16x8*)(A_lds + ((mt * 6 + f) * 64 + lane) * 8);
                acc0[mt] = __builtin_amdgcn_mfma_f32_16x16x32_bf16(a, wb1[0][f], acc0[mt], 0, 0, 0);
                acc1[mt] = __builtin_amdgcn_mfma_f32_16x16x32_bf16(a, wb1[1][f], acc1[mt], 0, 0, 0);
            }
#pragma unroll
        for (int mt = 0; mt < 4; ++mt)
#pragma unroll
            for (int r = 0; r < 4; ++r) {
                float v0 = acc0[mt][r]; v0 = v0 > 0.f ? v0 : 0.f;
                float v1 = acc1[mt][r]; v1 = v1 > 0.f ? v1 : 0.f;
                bf16x2 pk; pk[0] = (__bf16)v0; pk[1] = (__bf16)v1;
                int s = SWZ(g * 16 + r * 4 + (c >> 2));
                *(bf16x2*)&h_frag[((mt * 4 + w) * 512) + s * 8 + ((c & 3) << 1)] = pk;
            }
        __syncthreads();

        f32x4 acc2[4];
#pragma unroll
        for (int mt = 0; mt < 4; ++mt) acc2[mt] = mk4(b2v);
#pragma unroll
        for (int mt = 0; mt < 4; ++mt)
#pragma unroll
            for (int ks = 0; ks < 4; ++ks) {
                bf16x8 ah = *(const bf16x8*)&h_frag[(mt * 4 + ks) * 512 + sr * 8];
                acc2[mt] = __builtin_amdgcn_mfma_f32_16x16x32_bf16(ah, wb2[ks], acc2[mt], 0, 0, 0);
            }
#pragma unroll
        for (int mt = 0; mt < 4; ++mt)
#pragma unroll
            for (int r = 0; r < 4; ++r) {
                long orow = (long)t * 64 + mt * 16 + g * 4 + r;
                if (orow < E) out[orow * 64 + w * 16 + c] = acc2[mt][r];
            }
        __syncthreads();
    }
}

extern "C" void kernel_launch(void* const* d_in, const int* in_sizes, int n_in,
                              void* d_out, int out_size, void* d_ws, size_t ws_size,
                              hipStream_t stream) {
    const float* edge_feats = (const float*)d_in[0];
    const float* node_feats = (const float*)d_in[1];
    const float* gattr      = (const float*)d_in[2];
    const int*   senders    = (const int*)d_in[3];
    const int*   receivers  = (const int*)d_in[4];
    const float* W1         = (const float*)d_in[5];
    const float* b1         = (const float*)d_in[6];
    const float* W2         = (const float*)d_in[7];
    const float* b2         = (const float*)d_in[8];
    float* out = (float*)d_out;

    const int E = in_sizes[3];        // N_EDGES
    const int N = in_sizes[1] / 64;   // N_NODES

    char* ws = (char*)d_ws;
    __bf16* W1F = (__bf16*)ws;
    __bf16* W2F = (__bf16*)(ws + 49152);
    float*  g1  = (float*)(ws + 49152 + 16384);
    __bf16* nodeBF = (__bf16*)(ws + WS_NODEBF_OFF);

    const size_t ws_needed = (size_t)WS_NODEBF_OFF + (size_t)N * 64 * 2;
    const bool useNB = ws_size >= ws_needed;

    int prep_total = 128 * 192 + 64 * 128 + 128;
    prep_kernel<<<(prep_total + 255) / 256, 256, 0, stream>>>(W1, b1, W2, gattr, W1F, W2F, g1);

    const int numTiles = (E + 63) / 64;
    int grid = numTiles < GRID_MAIN ? numTiles : GRID_MAIN;
    if (useNB) {
        int n8 = N * 8;
        node_conv_kernel<<<(n8 + 255) / 256, 256, 0, stream>>>(node_feats, nodeBF, n8);
        edge_mlp_kernel<<<grid, 256, 0, stream>>>(edge_feats, nodeBF, senders, receivers,
                                                  W1F, W2F, g1, b2, out, E, numTiles);
    } else {
        edge_mlp_fallback<<<grid, 256, 0, stream>>>(edge_feats, node_feats, senders, receivers,
                                                    W1F, W2F, g1, b2, out, E, numTiles);
    }
}